// Round 9
// baseline (115.076 us; speedup 1.0000x reference)
//
#include <hip/hip_runtime.h>
#include <hip/hip_bf16.h>

#define NB 16
#define NCH 64
#define NT 2048

typedef __attribute__((ext_vector_type(8)))  short bf8;   // 8 bf16 (4 VGPRs) = MFMA A/B frag
typedef __attribute__((ext_vector_type(4)))  short bf4;
typedef __attribute__((ext_vector_type(16))) float f16f;  // 32x32 MFMA accumulator

#if defined(__has_builtin)
#if __has_builtin(__builtin_amdgcn_exp2f)
#define EXP2(x) __builtin_amdgcn_exp2f(x)
#else
#define EXP2(x) __expf((x) * 0.69314718056f)
#endif
#else
#define EXP2(x) __expf((x) * 0.69314718056f)
#endif

static __device__ __forceinline__ short f2b(float f) {
    unsigned u = __float_as_uint(f);
    u += 0x7fffu + ((u >> 16) & 1u);
    return (short)(u >> 16);
}

static __device__ __forceinline__ unsigned cvtpk(float lo, float hi) {
    unsigned r;
    asm("v_cvt_pk_bf16_f32 %0, %1, %2" : "=v"(r) : "v"(lo), "v"(hi));
    return r;
}
// v_permlane32_swap_b32 x, y : x.hi <-> y.lo.
// After: lanes<32 read y = partner(+32)'s x ; lanes>=32 read x = partner(-32)'s y.
#define SWAP32(x, y) asm volatile("v_permlane32_swap_b32 %0, %1" : "+v"(x), "+v"(y))

// ---- prep: Xw[b][t] = s2b1 * sum_c x ; xT[b][t][c] bf16 ; xn[b][c][t] bf16 ----
__global__ __launch_bounds__(256)
void prep_k(const float* __restrict__ x, const float* __restrict__ b1p,
            const float* __restrict__ w2,
            float* __restrict__ Xw, short* __restrict__ xT, short* __restrict__ xn) {
    __shared__ float T[NCH][65];
    const int b = blockIdx.y, t0 = blockIdx.x * 64;
    const int tid = threadIdx.x;
    const float* xb = x + (size_t)b * NCH * NT;

    const int tt = (tid & 15) * 4;
    #pragma unroll
    for (int co = 0; co < 4; ++co) {
        int c = co * 16 + (tid >> 4);
        float4 v = *reinterpret_cast<const float4*>(&xb[(size_t)c * NT + t0 + tt]);
        T[c][tt] = v.x; T[c][tt + 1] = v.y; T[c][tt + 2] = v.z; T[c][tt + 3] = v.w;
        bf4 w; w[0] = f2b(v.x); w[1] = f2b(v.y); w[2] = f2b(v.z); w[3] = f2b(v.w);
        *reinterpret_cast<bf4*>(&xn[((size_t)b * NCH + c) * NT + t0 + tt]) = w;
    }
    __syncthreads();
    if (tid < 64) {
        float s2b1 = 0.f;
        #pragma unroll
        for (int f = 0; f < 8; ++f) s2b1 += b1p[f] * w2[f];
        float s = 0.f;
        #pragma unroll
        for (int c = 0; c < NCH; ++c) s += T[c][tid];
        Xw[b * NT + t0 + tid] = s2b1 * s;
    }
    const int row = tid >> 2, cs = (tid & 3) * 16;
    bf8 v0, v1;
    #pragma unroll
    for (int u = 0; u < 8; ++u) v0[u] = f2b(T[cs + u][row]);
    #pragma unroll
    for (int u = 0; u < 8; ++u) v1[u] = f2b(T[cs + 8 + u][row]);
    short* dst = xT + ((size_t)b * NT + t0 + row) * NCH + cs;
    *reinterpret_cast<bf8*>(dst) = v0;
    *reinterpret_cast<bf8*>(dst + 8) = v1;
}

// ---- fused, all-register flash: 4 waves x (32 i-rows, j-quarter), 32x32 MFMA,
//      in-register softmax via cvt_pk + permlane32_swap. No LDS in hot loops. ----
__global__ __launch_bounds__(256)
void attn9_k(const float* __restrict__ w1, const float* __restrict__ w2,
             const float* __restrict__ gp,
             const float* __restrict__ Xw, const short* __restrict__ xT,
             const short* __restrict__ xn, const float* __restrict__ x,
             float* __restrict__ out) {
    __shared__ float mMn[4][32];
    __shared__ float mMx[4][32];
    __shared__ float mPS[4][32];
    __shared__ float mAcc[4][32][66];   // [wave][i][c], pad 66 (bank step 2 = free)

    const int b  = blockIdx.y;
    const int i0 = blockIdx.x * 32;
    const int tid  = threadIdx.x;
    const int h    = tid >> 6;          // wave: j-quarter [h*512, h*512+512)
    const int lane = tid & 63;
    const int il   = lane & 31;         // i-local / m-n index
    const int hi   = lane >> 5;
    const int hi8  = hi * 8;

    float s11 = 0.f;
    #pragma unroll
    for (int f = 0; f < 8; ++f) s11 += w1[f] * w2[f];
    const float g = gp[0];

    const short* xTb = xT + (size_t)b * NT * NCH;
    const short* xnb = xn + (size_t)b * NCH * NT;
    const float* xb  = x + (size_t)b * NCH * NT;
    const float* Xwb = Xw + b * NT;

    // constant B-frags (i-side of Gram^T): B[k=ch][n=i], ch = q*16 + hi8 + u
    const short* brow = xTb + (size_t)(i0 + il) * NCH + hi8;
    const bf8 Bg0 = *reinterpret_cast<const bf8*>(brow);
    const bf8 Bg1 = *reinterpret_cast<const bf8*>(brow + 16);
    const bf8 Bg2 = *reinterpret_cast<const bf8*>(brow + 32);
    const bf8 Bg3 = *reinterpret_cast<const bf8*>(brow + 48);

    float rmn = 3.0e38f, rmx = -3.0e38f;

    // ---------- pass 1: row min/max of e = s11*G + Xw[j] ----------
    for (int t = 0; t < 16; ++t) {
        const int jt = h * 512 + t * 32;
        const short* arow = xTb + (size_t)(jt + il) * NCH + hi8;
        bf8 a0 = *reinterpret_cast<const bf8*>(arow);
        bf8 a1 = *reinterpret_cast<const bf8*>(arow + 16);
        bf8 a2 = *reinterpret_cast<const bf8*>(arow + 32);
        bf8 a3 = *reinterpret_cast<const bf8*>(arow + 48);
        f16f acc = {0.f};
        acc = __builtin_amdgcn_mfma_f32_32x32x16_bf16(a0, Bg0, acc, 0, 0, 0);
        acc = __builtin_amdgcn_mfma_f32_32x32x16_bf16(a1, Bg1, acc, 0, 0, 0);
        acc = __builtin_amdgcn_mfma_f32_32x32x16_bf16(a2, Bg2, acc, 0, 0, 0);
        acc = __builtin_amdgcn_mfma_f32_32x32x16_bf16(a3, Bg3, acc, 0, 0, 0);
        const float4 tw0 = *reinterpret_cast<const float4*>(Xwb + jt + 4 * hi);
        const float4 tw1 = *reinterpret_cast<const float4*>(Xwb + jt + 8 + 4 * hi);
        const float4 tw2 = *reinterpret_cast<const float4*>(Xwb + jt + 16 + 4 * hi);
        const float4 tw3 = *reinterpret_cast<const float4*>(Xwb + jt + 24 + 4 * hi);
        const float tw[16] = { tw0.x, tw0.y, tw0.z, tw0.w, tw1.x, tw1.y, tw1.z, tw1.w,
                               tw2.x, tw2.y, tw2.z, tw2.w, tw3.x, tw3.y, tw3.z, tw3.w };
        #pragma unroll
        for (int r = 0; r < 16; ++r) {
            float e = fmaf(s11, acc[r], tw[r]);
            rmn = fminf(rmn, e);
            rmx = fmaxf(rmx, e);
        }
    }
    rmn = fminf(rmn, __shfl_xor(rmn, 32, 64));
    rmx = fmaxf(rmx, __shfl_xor(rmx, 32, 64));
    if (lane < 32) { mMn[h][lane] = rmn; mMx[h][lane] = rmx; }
    __syncthreads();

    float mn = mMn[0][il], mx = mMx[0][il];
    #pragma unroll
    for (int w = 1; w < 4; ++w) {
        mn = fminf(mn, mMn[w][il]);
        mx = fmaxf(mx, mMx[w][il]);
    }
    const float inv2 = 1.44269504f / (mx - mn + 1e-8f);
    const float A  = s11 * inv2;
    const float KI = -mn * inv2;

    f16f macc0 = {0.f}, macc1 = {0.f};
    float ps = 0.f;

    // ---------- pass 2: Gram -> exp2 -> in-register P (cvt_pk + permlane) -> mixed ----------
    for (int t = 0; t < 16; ++t) {
        const int jt = h * 512 + t * 32;
        const short* arow = xTb + (size_t)(jt + il) * NCH + hi8;
        bf8 a0 = *reinterpret_cast<const bf8*>(arow);
        bf8 a1 = *reinterpret_cast<const bf8*>(arow + 16);
        bf8 a2 = *reinterpret_cast<const bf8*>(arow + 32);
        bf8 a3 = *reinterpret_cast<const bf8*>(arow + 48);
        f16f acc = {0.f};
        acc = __builtin_amdgcn_mfma_f32_32x32x16_bf16(a0, Bg0, acc, 0, 0, 0);
        acc = __builtin_amdgcn_mfma_f32_32x32x16_bf16(a1, Bg1, acc, 0, 0, 0);
        acc = __builtin_amdgcn_mfma_f32_32x32x16_bf16(a2, Bg2, acc, 0, 0, 0);
        acc = __builtin_amdgcn_mfma_f32_32x32x16_bf16(a3, Bg3, acc, 0, 0, 0);
        const float4 tw0 = *reinterpret_cast<const float4*>(Xwb + jt + 4 * hi);
        const float4 tw1 = *reinterpret_cast<const float4*>(Xwb + jt + 8 + 4 * hi);
        const float4 tw2 = *reinterpret_cast<const float4*>(Xwb + jt + 16 + 4 * hi);
        const float4 tw3 = *reinterpret_cast<const float4*>(Xwb + jt + 24 + 4 * hi);
        const float tw[16] = { tw0.x, tw0.y, tw0.z, tw0.w, tw1.x, tw1.y, tw1.z, tw1.w,
                               tw2.x, tw2.y, tw2.z, tw2.w, tw3.x, tw3.y, tw3.z, tw3.w };
        float p[16];
        #pragma unroll
        for (int r = 0; r < 16; ++r) {
            p[r] = EXP2(fmaf(A, acc[r], fmaf(tw[r], inv2, KI)));
            ps += p[r];
        }
        // pack: pk[jn][h2] covers j = jt + 8*jn + 4*hi + 2*h2 + {0,1}
        unsigned pk00 = cvtpk(p[0],  p[1]),  pk01 = cvtpk(p[2],  p[3]);
        unsigned pk10 = cvtpk(p[4],  p[5]),  pk11 = cvtpk(p[6],  p[7]);
        unsigned pk20 = cvtpk(p[8],  p[9]),  pk21 = cvtpk(p[10], p[11]);
        unsigned pk30 = cvtpk(p[12], p[13]), pk31 = cvtpk(p[14], p[15]);
        // lane-transpose so lane holds P[i=il][j = 16*ks + hi8 + u]
        SWAP32(pk00, pk10); SWAP32(pk01, pk11);
        SWAP32(pk20, pk30); SWAP32(pk21, pk31);
        union { unsigned u[4]; bf8 v; } f0, f1;
        f0.u[0] = pk00; f0.u[1] = pk01; f0.u[2] = pk10; f0.u[3] = pk11;  // k = j-jt in [0,16)
        f1.u[0] = pk20; f1.u[1] = pk21; f1.u[2] = pk30; f1.u[3] = pk31;  // k in [16,32)
        // mixed: macc[c][i] += sum_j xn[c][j] * P[i][j]
        const short* xrow0 = xnb + (size_t)(il) * NT + jt + hi8;         // cb=0: c = il
        const short* xrow1 = xnb + (size_t)(32 + il) * NT + jt + hi8;    // cb=1: c = 32+il
        bf8 m00 = *reinterpret_cast<const bf8*>(xrow0);
        bf8 m01 = *reinterpret_cast<const bf8*>(xrow0 + 16);
        bf8 m10 = *reinterpret_cast<const bf8*>(xrow1);
        bf8 m11 = *reinterpret_cast<const bf8*>(xrow1 + 16);
        macc0 = __builtin_amdgcn_mfma_f32_32x32x16_bf16(m00, f0.v, macc0, 0, 0, 0);
        macc0 = __builtin_amdgcn_mfma_f32_32x32x16_bf16(m01, f1.v, macc0, 0, 0, 0);
        macc1 = __builtin_amdgcn_mfma_f32_32x32x16_bf16(m10, f0.v, macc1, 0, 0, 0);
        macc1 = __builtin_amdgcn_mfma_f32_32x32x16_bf16(m11, f1.v, macc1, 0, 0, 0);
    }

    ps += __shfl_xor(ps, 32, 64);
    if (lane < 32) mPS[h][lane] = ps;

    // scatter macc to LDS: c = (r&3) + 8*(r>>2) + 4*hi + 32*cb, i = il
    #pragma unroll
    for (int r = 0; r < 16; ++r) {
        const int c = (r & 3) + 8 * (r >> 2) + 4 * hi;
        mAcc[h][il][c]      = macc0[r];
        mAcc[h][il][c + 32] = macc1[r];
    }
    __syncthreads();

    // epilogue: thread (grp = tid>>5, i_l = tid&31) -> c = grp*8+u
    const int i_l = tid & 31, grp = tid >> 5;
    const float rs = mPS[0][i_l] + mPS[1][i_l] + mPS[2][i_l] + mPS[3][i_l];
    const float sc = g / rs;
    const int i = i0 + i_l;
    #pragma unroll
    for (int u = 0; u < 8; ++u) {
        const int c = grp * 8 + u;
        const float tot = mAcc[0][i_l][c] + mAcc[1][i_l][c]
                        + mAcc[2][i_l][c] + mAcc[3][i_l][c];
        out[((size_t)b * NCH + c) * NT + i] = fmaf(sc, tot, xb[(size_t)c * NT + i]);
    }
}

extern "C" void kernel_launch(void* const* d_in, const int* in_sizes, int n_in,
                              void* d_out, int out_size, void* d_ws, size_t ws_size,
                              hipStream_t stream) {
    const float* x     = (const float*)d_in[0];
    const float* w1    = (const float*)d_in[1];
    const float* b1    = (const float*)d_in[2];
    const float* w2    = (const float*)d_in[3];
    const float* gamma = (const float*)d_in[5];
    float* out = (float*)d_out;

    char* p = (char*)d_ws;
    float* Xw = (float*)p;   p += (size_t)NB * NT * 4;        // 128 KB
    short* xT = (short*)p;   p += (size_t)NB * NT * NCH * 2;  // 4 MB
    short* xn = (short*)p;                                     // 4 MB

    hipLaunchKernelGGL(prep_k, dim3(NT / 64, NB), dim3(256), 0, stream,
                       x, b1, w2, Xw, xT, xn);
    hipLaunchKernelGGL(attn9_k, dim3(NT / 32, NB), dim3(256), 0, stream,
                       w1, w2, gamma, Xw, xT, xn, x, out);
}